// Round 2
// baseline (490.419 us; speedup 1.0000x reference)
//
#include <hip/hip_runtime.h>
#include <hip/hip_bf16.h>

// GraphSAGE fused kernels for MI355X (gfx950).
// N=768, NODE_IN=64, EDGE_IN=32, H=128, ROUNDS=2.
//
// Round 2: software-pipelined k_big (double-buffered ef staging, register
// prefetch of ef + C-init, 2 barriers/chunk), s_proj precomputed in MFMA
// C-fragment layout (spF), occupancy 2->3 blocks/CU, small kernels fused.

typedef __bf16 bf16x8 __attribute__((ext_vector_type(8)));
typedef float f32x4 __attribute__((ext_vector_type(4)));

#define NN   768
#define FEF  32

static __device__ __forceinline__ unsigned short to_bf16u(float x) {
    return __builtin_bit_cast(unsigned short, (__bf16)x);
}

// s_proj fragment-layout flat index: value (i,k) lands where wave/lane math
// in k_big expects it: i = 64*ic+32*wr+16*rt+4*lg+r ; k = 64*wc+16*t+lr
__device__ __forceinline__ int spf_idx(int i, int k) {
    int ic = i >> 6, i6 = i & 63;
    int wr = i6 >> 5, rt = (i6 >> 4) & 1, lg = (i6 >> 2) & 3, r = i6 & 3;
    int wc = k >> 6, tt = (k >> 4) & 3, lr = k & 15;
    int lane = 16 * lg + lr;
    return ((((((ic * 2 + wr) * 2 + rt) * 2 + wc) * 4 + tt) * 64 + lane) << 2) + r;
}

// ---------------------------------------------------------------- fused prep
// blocks 0..575   : adj transpose (32x32 tiles)
// blocks 576..655 : weight transposes We->WeT, Wa[H:]->Wa2T (bf16 k-minor)
// blocks 656..1039: h0 = relu(nf@Wn+bn) and spF = frag-layout(h0@Wa[:H]+ba)
__global__ void k_prep(const float* __restrict__ adj, float* __restrict__ adjT,
                       const float* __restrict__ We, const float* __restrict__ Wa,
                       unsigned short* __restrict__ WeT, unsigned short* __restrict__ Wa2T,
                       const float* __restrict__ nf, const float* __restrict__ Wn,
                       const float* __restrict__ bn, const float* __restrict__ ba,
                       float* __restrict__ h, float* __restrict__ spF) {
    const int b = blockIdx.x, tid = threadIdx.x;
    if (b < 576) {
        __shared__ float tile[32][33];
        int bx = b % 24, by = b / 24;
        int tx = tid & 31, ty = tid >> 5;  // 32 x 8
#pragma unroll
        for (int yy = 0; yy < 32; yy += 8)
            tile[ty + yy][tx] = adj[(size_t)(by * 32 + ty + yy) * NN + bx * 32 + tx];
        __syncthreads();
#pragma unroll
        for (int yy = 0; yy < 32; yy += 8)
            adjT[(size_t)(bx * 32 + ty + yy) * NN + by * 32 + tx] = tile[tx][ty + yy];
    } else if (b < 656) {
        int g = (b - 576) * 256 + tid;
        if (g < 128 * 32) {
            int c = g >> 5, f = g & 31;
            WeT[g] = to_bf16u(We[f * 128 + c]);
        } else {
            int g2 = g - 128 * 32;
            int c = g2 >> 7, k = g2 & 127;
            Wa2T[g2] = to_bf16u(Wa[(128 + k) * 128 + c]);
        }
    } else {
        __shared__ float nf_l[2][64];
        __shared__ float h_l[2][128];
        int row = tid >> 7, t = tid & 127;
        int i = (b - 656) * 2 + row;
        if (t < 64) nf_l[row][t] = nf[i * 64 + t];
        __syncthreads();
        float acc = bn[t];
#pragma unroll 8
        for (int f = 0; f < 64; ++f) acc += nf_l[row][f] * Wn[f * 128 + t];
        acc = fmaxf(acc, 0.f);
        h[i * 128 + t] = acc;
        h_l[row][t] = acc;
        __syncthreads();
        float sp = ba[t];
#pragma unroll 8
        for (int f = 0; f < 128; ++f) sp += h_l[row][f] * Wa[f * 128 + t];
        spF[spf_idx(i, t)] = sp;
    }
}

// ---------------------------------------------------------------- the big fused kernel
// One block per receiver j. 4 waves in 2x2. Software-pipelined chunks of 64 senders.
__global__ __launch_bounds__(256, 3) void k_big(
    const float* __restrict__ ef, const float* __restrict__ adjT,
    const float* __restrict__ spF, const unsigned short* __restrict__ WeT,
    const unsigned short* __restrict__ Wa2T, const float* __restrict__ be,
    float* __restrict__ agg) {
    __shared__ unsigned short ef_lds[2][64 * 40];  // 2 x 5KB, padded stride 80B
    __shared__ unsigned short E_lds[64 * 128];     // 16KB, XOR-swizzled bf16
    __shared__ float adj_lds[NN];
    __shared__ float red[4][128];
    __shared__ float wred[4];
    __shared__ float s_invdeg;

    const int tid  = threadIdx.x;
    const int j    = blockIdx.x;
    const int lane = tid & 63;
    const int wave = tid >> 6;
    const int wr = wave >> 1, wc = wave & 1;
    const int lg = lane >> 4;
    const int lr = lane & 15;

    // stage adj column j (row of adjT) + degree
    float asum = 0.f;
    for (int k = tid; k < NN; k += 256) {
        float a = adjT[(size_t)j * NN + k];
        adj_lds[k] = a;
        asum += a;
    }
#pragma unroll
    for (int off = 32; off; off >>= 1) asum += __shfl_down(asum, off);
    if (lane == 0) wred[wave] = asum;

    // hoist weight B-fragments (constant across chunks)
    bf16x8 bwe[4];
    bf16x8 bwa[4][4];
    float bereg[4];
#pragma unroll
    for (int t = 0; t < 4; ++t) {
        int col = 64 * wc + 16 * t + lr;
        bwe[t] = *reinterpret_cast<const bf16x8*>(WeT + col * 32 + 8 * lg);
        bereg[t] = be[col];
#pragma unroll
        for (int s = 0; s < 4; ++s)
            bwa[t][s] = *reinterpret_cast<const bf16x8*>(Wa2T + col * 128 + 32 * s + 8 * lg);
    }

    // stage chunk 0 directly; prefetch chunk 1 into registers
    const int r_st = tid >> 2;
    const int c_st = (tid & 3) * 8;
    {
        const float* src = ef + (size_t)r_st * (NN * FEF) + j * FEF + c_st;
        float4 f0 = *reinterpret_cast<const float4*>(src);
        float4 f1 = *reinterpret_cast<const float4*>(src + 4);
        bf16x8 v;
        v[0] = (__bf16)f0.x; v[1] = (__bf16)f0.y; v[2] = (__bf16)f0.z; v[3] = (__bf16)f0.w;
        v[4] = (__bf16)f1.x; v[5] = (__bf16)f1.y; v[6] = (__bf16)f1.z; v[7] = (__bf16)f1.w;
        *reinterpret_cast<bf16x8*>(&ef_lds[0][r_st * 40 + c_st]) = v;
    }
    float4 p0, p1;
    {
        const float* src = ef + (size_t)(64 + r_st) * (NN * FEF) + j * FEF + c_st;
        p0 = *reinterpret_cast<const float4*>(src);
        p1 = *reinterpret_cast<const float4*>(src + 4);
    }
    __syncthreads();
    if (tid == 0) s_invdeg = 1.0f / fmaxf(wred[0] + wred[1] + wred[2] + wred[3], 1.0f);

    float aggp[4] = {0.f, 0.f, 0.f, 0.f};

#pragma unroll 2
    for (int n = 0; n < 12; ++n) {
        const int b = n & 1;
        const int ibase = n * 64;

        // prefetch this chunk's C-init (s_proj+ba) in frag layout
        f32x4 spv[2][4];
#pragma unroll
        for (int rt = 0; rt < 2; ++rt)
#pragma unroll
            for (int t = 0; t < 4; ++t)
                spv[rt][t] = *reinterpret_cast<const f32x4*>(
                    spF + (((((((n * 2 + wr) * 2 + rt) * 2 + wc) * 4 + t) * 64) + lane) << 2));

        // ---- A: GEMM1 E = relu(EF @ We + be)
        f32x4 C1[2][4];
#pragma unroll
        for (int rt = 0; rt < 2; ++rt) {
            bf16x8 a = *reinterpret_cast<const bf16x8*>(&ef_lds[b][(32 * wr + 16 * rt + lr) * 40 + 8 * lg]);
#pragma unroll
            for (int t = 0; t < 4; ++t) {
                f32x4 c;
                c[0] = bereg[t]; c[1] = bereg[t]; c[2] = bereg[t]; c[3] = bereg[t];
                C1[rt][t] = __builtin_amdgcn_mfma_f32_16x16x32_bf16(a, bwe[t], c, 0, 0, 0);
            }
        }
#pragma unroll
        for (int rt = 0; rt < 2; ++rt)
#pragma unroll
            for (int t = 0; t < 4; ++t)
#pragma unroll
                for (int r = 0; r < 4; ++r) {
                    int grow = 32 * wr + 16 * rt + 4 * lg + r;
                    int gcol = 64 * wc + 16 * t + lr;
                    int idx = (grow * 128 + gcol) ^ ((grow & 7) << 3);
                    E_lds[idx] = to_bf16u(fmaxf(C1[rt][t][r], 0.f));
                }
        __syncthreads();

        // ---- B: write next ef chunk from prefetch regs, reload prefetch
        if (n < 11) {
            bf16x8 v;
            v[0] = (__bf16)p0.x; v[1] = (__bf16)p0.y; v[2] = (__bf16)p0.z; v[3] = (__bf16)p0.w;
            v[4] = (__bf16)p1.x; v[5] = (__bf16)p1.y; v[6] = (__bf16)p1.z; v[7] = (__bf16)p1.w;
            *reinterpret_cast<bf16x8*>(&ef_lds[b ^ 1][r_st * 40 + c_st]) = v;
        }
        if (n < 10) {
            const float* src = ef + (size_t)(ibase + 128 + r_st) * (NN * FEF) + j * FEF + c_st;
            p0 = *reinterpret_cast<const float4*>(src);
            p1 = *reinterpret_cast<const float4*>(src + 4);
        }

        // ---- GEMM2: P = E @ Wa2 + (s_proj+ba), relu, adj-weight, accumulate
#pragma unroll
        for (int rt = 0; rt < 2; ++rt) {
            bf16x8 ae[4];
            int grow = 32 * wr + 16 * rt + lr;
#pragma unroll
            for (int s = 0; s < 4; ++s) {
                int off = (grow * 128 + 32 * s + 8 * lg) ^ ((grow & 7) << 3);
                ae[s] = *reinterpret_cast<const bf16x8*>(E_lds + off);
            }
            int i0 = ibase + 32 * wr + 16 * rt + 4 * lg;
            float av[4];
#pragma unroll
            for (int r = 0; r < 4; ++r) av[r] = adj_lds[i0 + r];
#pragma unroll
            for (int t = 0; t < 4; ++t) {
                f32x4 C2 = spv[rt][t];
#pragma unroll
                for (int s = 0; s < 4; ++s)
                    C2 = __builtin_amdgcn_mfma_f32_16x16x32_bf16(ae[s], bwa[t][s], C2, 0, 0, 0);
#pragma unroll
                for (int r = 0; r < 4; ++r)
                    aggp[t] += fmaxf(C2[r], 0.f) * av[r];
            }
        }
        __syncthreads();
    }

    // reduce partials: lanes l, l+16, l+32, l+48 share a column
#pragma unroll
    for (int t = 0; t < 4; ++t) {
        float v = aggp[t];
        v += __shfl_xor(v, 16);
        v += __shfl_xor(v, 32);
        if (lane < 16) red[wave][64 * wc + 16 * t + lane] = v;
    }
    __syncthreads();
    if (tid < 128) {
        int col = tid, w = col >> 6;
        agg[(size_t)j * 128 + col] = (red[w][col] + red[w + 2][col]) * s_invdeg;
    }
}

// ---------------------------------------------------------------- update (+ next-round spF, or final out)
template <int LAST>
__global__ void k_upd(const float* __restrict__ h_in, const float* __restrict__ agg,
                      const float* __restrict__ Wu, const float* __restrict__ bu,
                      const float* __restrict__ Wa, const float* __restrict__ ba,
                      float* __restrict__ h_out, float* __restrict__ spF,
                      float* __restrict__ out) {
    __shared__ float buf[2][256];
    __shared__ float hn[2][128];
    const int tid = threadIdx.x;
    const int row = tid >> 7, t = tid & 127;
    const int i = blockIdx.x * 2 + row;
    buf[row][t] = h_in[i * 128 + t];
    buf[row][128 + t] = agg[i * 128 + t];
    __syncthreads();
    float acc = bu[t];
#pragma unroll 8
    for (int f = 0; f < 256; ++f) acc += buf[row][f] * Wu[f * 128 + t];
    acc = fmaxf(acc, 0.f);
    if (LAST) {
        out[i * 128 + t] = acc;
    } else {
        h_out[i * 128 + t] = acc;
        hn[row][t] = acc;
        __syncthreads();
        float sp = ba[t];
#pragma unroll 8
        for (int f = 0; f < 128; ++f) sp += hn[row][f] * Wa[f * 128 + t];
        spF[spf_idx(i, t)] = sp;
    }
}

// ---------------------------------------------------------------- graph embedding (reads h from out)
__global__ void k_gemb(const float* __restrict__ out_h, float* __restrict__ out) {
    int c = blockIdx.x, l = threadIdx.x;
    float acc = 0.f;
    for (int i = l; i < NN; i += 64) acc += out_h[(size_t)i * 128 + c];
#pragma unroll
    for (int off = 32; off; off >>= 1) acc += __shfl_down(acc, off);
    if (l == 0) out[NN * 128 + c] = acc * (1.0f / 768.0f);
}

extern "C" void kernel_launch(void* const* d_in, const int* in_sizes, int n_in,
                              void* d_out, int out_size, void* d_ws, size_t ws_size,
                              hipStream_t stream) {
    const float* nf  = (const float*)d_in[0];
    const float* ef  = (const float*)d_in[1];
    const float* adj = (const float*)d_in[2];
    const float* Wn  = (const float*)d_in[3];
    const float* bn  = (const float*)d_in[4];
    const float* We  = (const float*)d_in[5];
    const float* be  = (const float*)d_in[6];
    const float* Wa  = (const float*)d_in[7];
    const float* ba  = (const float*)d_in[8];
    const float* Wu  = (const float*)d_in[9];
    const float* bu  = (const float*)d_in[10];
    float* out = (float*)d_out;

    // workspace carve-up (floats): h | agg | spF | adjT | WeT(bf16) | Wa2T(bf16)
    float* h_buf = (float*)d_ws;
    float* agg   = h_buf + NN * 128;
    float* spF   = agg + NN * 128;
    float* adjT  = spF + NN * 128;
    unsigned short* WeT  = (unsigned short*)(adjT + NN * NN);
    unsigned short* Wa2T = WeT + 128 * 32;

    k_prep<<<1040, 256, 0, stream>>>(adj, adjT, We, Wa, WeT, Wa2T, nf, Wn, bn, ba, h_buf, spF);

    k_big<<<NN, 256, 0, stream>>>(ef, adjT, spF, WeT, Wa2T, be, agg);
    k_upd<0><<<NN / 2, 256, 0, stream>>>(h_buf, agg, Wu, bu, Wa, ba, h_buf, spF, out);
    k_big<<<NN, 256, 0, stream>>>(ef, adjT, spF, WeT, Wa2T, be, agg);
    k_upd<1><<<NN / 2, 256, 0, stream>>>(h_buf, agg, Wu, bu, Wa, ba, h_buf, spF, out);

    k_gemb<<<128, 64, 0, stream>>>(out, out);
}

// Round 3
// 237.125 us; speedup vs baseline: 2.0682x; 2.0682x over previous
//
#include <hip/hip_runtime.h>
#include <hip/hip_bf16.h>

// GraphSAGE fused kernels for MI355X (gfx950).
// N=768, NODE_IN=64, EDGE_IN=32, H=128, ROUNDS=2.
//
// Round 3: barrier-free k_big. Block = receiver j, 4 independent waves,
// each wave owns disjoint 16-row sender chunks end-to-end (global A-frag ->
// GEMM1 -> private LDS E -> GEMM2 -> adj-weighted accumulate). No
// __syncthreads in the main loop; Wa2 B-frags served from a block-shared
// XOR-swizzled LDS copy. No launch_bounds occupancy gamble (spill lesson
// from round 2): (256,2) cap only, state kept lean.

typedef __bf16 bf16x8 __attribute__((ext_vector_type(8)));
typedef float f32x4 __attribute__((ext_vector_type(4)));

#define NN 768

static __device__ __forceinline__ unsigned short to_bf16u(float x) {
    return __builtin_bit_cast(unsigned short, (__bf16)x);
}

// s_proj fragment layout: i = 16*ng + 4*lg + r ; k = 16*t + lr
__device__ __forceinline__ int spf_idx(int i, int k) {
    int ng = i >> 4, lg = (i >> 2) & 3, r = i & 3;
    int t = k >> 4, lr = k & 15;
    return (((ng * 8 + t) * 64 + 16 * lg + lr) << 2) + r;
}

// ---------------------------------------------------------------- fused prep
// blocks 0..575   : adj transpose (32x32 tiles)
// blocks 576..655 : weight transposes We->WeT, Wa[H:]->Wa2T (bf16 k-minor)
// blocks 656..1039: h0 = relu(nf@Wn+bn) and spF = frag-layout(h0@Wa[:H]+ba)
__global__ void k_prep(const float* __restrict__ adj, float* __restrict__ adjT,
                       const float* __restrict__ We, const float* __restrict__ Wa,
                       unsigned short* __restrict__ WeT, unsigned short* __restrict__ Wa2T,
                       const float* __restrict__ nf, const float* __restrict__ Wn,
                       const float* __restrict__ bn, const float* __restrict__ ba,
                       float* __restrict__ h, float* __restrict__ spF) {
    const int b = blockIdx.x, tid = threadIdx.x;
    if (b < 576) {
        __shared__ float tile[32][33];
        int bx = b % 24, by = b / 24;
        int tx = tid & 31, ty = tid >> 5;  // 32 x 8
#pragma unroll
        for (int yy = 0; yy < 32; yy += 8)
            tile[ty + yy][tx] = adj[(size_t)(by * 32 + ty + yy) * NN + bx * 32 + tx];
        __syncthreads();
#pragma unroll
        for (int yy = 0; yy < 32; yy += 8)
            adjT[(size_t)(bx * 32 + ty + yy) * NN + by * 32 + tx] = tile[tx][ty + yy];
    } else if (b < 656) {
        int g = (b - 576) * 256 + tid;
        if (g < 128 * 32) {
            int c = g >> 5, f = g & 31;
            WeT[g] = to_bf16u(We[f * 128 + c]);
        } else {
            int g2 = g - 128 * 32;
            int c = g2 >> 7, k = g2 & 127;
            Wa2T[g2] = to_bf16u(Wa[(128 + k) * 128 + c]);
        }
    } else {
        __shared__ float nf_l[2][64];
        __shared__ float h_l[2][128];
        int row = tid >> 7, t = tid & 127;
        int i = (b - 656) * 2 + row;
        if (t < 64) nf_l[row][t] = nf[i * 64 + t];
        __syncthreads();
        float acc = bn[t];
#pragma unroll 8
        for (int f = 0; f < 64; ++f) acc += nf_l[row][f] * Wn[f * 128 + t];
        acc = fmaxf(acc, 0.f);
        h[i * 128 + t] = acc;
        h_l[row][t] = acc;
        __syncthreads();
        float sp = ba[t];
#pragma unroll 8
        for (int f = 0; f < 128; ++f) sp += h_l[row][f] * Wa[f * 128 + t];
        spF[spf_idx(i, t)] = sp;
    }
}

// ---------------------------------------------------------------- the big fused kernel
__global__ __launch_bounds__(256, 2) void k_big(
    const float* __restrict__ ef, const float* __restrict__ adjT,
    const float* __restrict__ spF, const unsigned short* __restrict__ WeT,
    const unsigned short* __restrict__ Wa2T, const float* __restrict__ be,
    float* __restrict__ agg) {
    __shared__ unsigned short wa2_lds[128 * 128];   // 32KB, XOR-swizzled
    __shared__ unsigned short e_lds[4][16 * 128];   // 4KB per wave, private
    __shared__ float adj_lds[NN];                   // 3KB
    __shared__ float wred[4];
    __shared__ float s_invdeg;

    const int tid  = threadIdx.x;
    const int j    = blockIdx.x;
    const int lane = tid & 63;
    const int wv   = tid >> 6;
    const int lg   = lane >> 4;
    const int lr   = lane & 15;

    // ---- stage Wa2T -> swizzled LDS (each thread: 64 consecutive shorts)
    {
        const int col = tid >> 1;
        const int kb  = (tid & 1) * 64;
#pragma unroll
        for (int m = 0; m < 8; ++m) {
            bf16x8 v = *reinterpret_cast<const bf16x8*>(Wa2T + col * 128 + kb + 8 * m);
            int idx = (col * 128 + kb + 8 * m) ^ ((col & 7) << 3);
            *reinterpret_cast<bf16x8*>(&wa2_lds[idx]) = v;
        }
    }
    // ---- adj column j + degree
    float asum = 0.f;
    for (int k = tid; k < NN; k += 256) {
        float a = adjT[(size_t)j * NN + k];
        adj_lds[k] = a;
        asum += a;
    }
#pragma unroll
    for (int off = 32; off; off >>= 1) asum += __shfl_down(asum, off);
    if (lane == 0) wred[wv] = asum;

    // ---- GEMM1 B-frags (We), all 8 col-tiles
    bf16x8 bwe[8];
    float bereg[8];
#pragma unroll
    for (int t = 0; t < 8; ++t) {
        int col = 16 * t + lr;
        bwe[t] = *reinterpret_cast<const bf16x8*>(WeT + col * 32 + 8 * lg);
        bereg[t] = be[col];
    }
    __syncthreads();
    if (tid == 0) s_invdeg = 1.0f / fmaxf(wred[0] + wred[1] + wred[2] + wred[3], 1.0f);

    float aggp[8] = {0.f, 0.f, 0.f, 0.f, 0.f, 0.f, 0.f, 0.f};

    // ef row pointer for this lane: row = 16*ng + lr, feats 8*lg..8*lg+7 (fp32)
    const float* efbase = ef + ((size_t)lr * NN + j) * 32 + 8 * lg;
    const size_t row16 = (size_t)16 * NN * 32;   // 16 rows stride in floats

    // preload chunk 0 (ng = wv)
    float4 a0 = *reinterpret_cast<const float4*>(efbase + (size_t)wv * row16);
    float4 a1 = *reinterpret_cast<const float4*>(efbase + (size_t)wv * row16 + 4);

    // ---- barrier-free main loop: 12 private 16-row chunks per wave
    for (int n = 0; n < 12; ++n) {
        const int ng = wv + 4 * n;
        const int i0 = 16 * ng;

        bf16x8 a;
        a[0] = (__bf16)a0.x; a[1] = (__bf16)a0.y; a[2] = (__bf16)a0.z; a[3] = (__bf16)a0.w;
        a[4] = (__bf16)a1.x; a[5] = (__bf16)a1.y; a[6] = (__bf16)a1.z; a[7] = (__bf16)a1.w;

        float4 nx0, nx1;
        if (n < 11) {
            const float* p = efbase + (size_t)(ng + 4) * row16;
            nx0 = *reinterpret_cast<const float4*>(p);
            nx1 = *reinterpret_cast<const float4*>(p + 4);
        }

        // C-init (s_proj + ba) in fragment layout, coalesced
        f32x4 spv[8];
#pragma unroll
        for (int t = 0; t < 8; ++t)
            spv[t] = *reinterpret_cast<const f32x4*>(spF + ((((ng * 8 + t) * 64) + lane) << 2));

        f32x4 av = *reinterpret_cast<const f32x4*>(&adj_lds[i0 + 4 * lg]);

        // GEMM1: E(16x128) = relu(EF @ We + be)
        f32x4 C1[8];
#pragma unroll
        for (int t = 0; t < 8; ++t) {
            f32x4 c;
            c[0] = bereg[t]; c[1] = bereg[t]; c[2] = bereg[t]; c[3] = bereg[t];
            C1[t] = __builtin_amdgcn_mfma_f32_16x16x32_bf16(a, bwe[t], c, 0, 0, 0);
        }
        // write E to private swizzled LDS region (wave-synchronous)
#pragma unroll
        for (int t = 0; t < 8; ++t)
#pragma unroll
            for (int r = 0; r < 4; ++r) {
                int row = 4 * lg + r, col = 16 * t + lr;
                int idx = (row * 128 + col) ^ ((row & 7) << 3);
                e_lds[wv][idx] = to_bf16u(fmaxf(C1[t][r], 0.f));
            }
        // GEMM2 A-frags from private E
        bf16x8 ae[4];
#pragma unroll
        for (int s = 0; s < 4; ++s) {
            int idx = (lr * 128 + 32 * s + 8 * lg) ^ ((lr & 7) << 3);
            ae[s] = *reinterpret_cast<const bf16x8*>(&e_lds[wv][idx]);
        }
        // GEMM2: P = E @ Wa2 + s_proj, relu, adj-weight, accumulate
#pragma unroll
        for (int t = 0; t < 8; ++t) {
            f32x4 acc = spv[t];
            const int col = 16 * t + lr;
#pragma unroll
            for (int s = 0; s < 4; ++s) {
                int widx = (col * 128 + 32 * s + 8 * lg) ^ ((col & 7) << 3);
                bf16x8 bw = *reinterpret_cast<const bf16x8*>(&wa2_lds[widx]);
                acc = __builtin_amdgcn_mfma_f32_16x16x32_bf16(ae[s], bw, acc, 0, 0, 0);
            }
#pragma unroll
            for (int r = 0; r < 4; ++r)
                aggp[t] += fmaxf(acc[r], 0.f) * av[r];
        }

        if (n < 11) { a0 = nx0; a1 = nx1; }
    }

    // ---- reduce: sum over lg groups, then across waves (reuse e_lds as red)
    float* redw = reinterpret_cast<float*>(&e_lds[wv][0]);
#pragma unroll
    for (int t = 0; t < 8; ++t) {
        float v = aggp[t];
        v += __shfl_xor(v, 16);
        v += __shfl_xor(v, 32);
        if (lane < 16) redw[16 * t + lane] = v;
    }
    __syncthreads();
    if (tid < 128) {
        const float* r0 = reinterpret_cast<const float*>(&e_lds[0][0]);
        const float* r1 = reinterpret_cast<const float*>(&e_lds[1][0]);
        const float* r2 = reinterpret_cast<const float*>(&e_lds[2][0]);
        const float* r3 = reinterpret_cast<const float*>(&e_lds[3][0]);
        agg[(size_t)j * 128 + tid] = (r0[tid] + r1[tid] + r2[tid] + r3[tid]) * s_invdeg;
    }
}

// ---------------------------------------------------------------- update (+ next-round spF, or final out)
template <int LAST>
__global__ void k_upd(const float* __restrict__ h_in, const float* __restrict__ agg,
                      const float* __restrict__ Wu, const float* __restrict__ bu,
                      const float* __restrict__ Wa, const float* __restrict__ ba,
                      float* __restrict__ h_out, float* __restrict__ spF,
                      float* __restrict__ out) {
    __shared__ float buf[2][256];
    __shared__ float hn[2][128];
    const int tid = threadIdx.x;
    const int row = tid >> 7, t = tid & 127;
    const int i = blockIdx.x * 2 + row;
    buf[row][t] = h_in[i * 128 + t];
    buf[row][128 + t] = agg[i * 128 + t];
    __syncthreads();
    float acc = bu[t];
#pragma unroll 8
    for (int f = 0; f < 256; ++f) acc += buf[row][f] * Wu[f * 128 + t];
    acc = fmaxf(acc, 0.f);
    if (LAST) {
        out[i * 128 + t] = acc;
    } else {
        h_out[i * 128 + t] = acc;
        hn[row][t] = acc;
        __syncthreads();
        float sp = ba[t];
#pragma unroll 8
        for (int f = 0; f < 128; ++f) sp += hn[row][f] * Wa[f * 128 + t];
        spF[spf_idx(i, t)] = sp;
    }
}

// ---------------------------------------------------------------- graph embedding (reads h from out)
__global__ void k_gemb(const float* __restrict__ out_h, float* __restrict__ out) {
    int c = blockIdx.x, l = threadIdx.x;
    float acc = 0.f;
    for (int i = l; i < NN; i += 64) acc += out_h[(size_t)i * 128 + c];
#pragma unroll
    for (int off = 32; off; off >>= 1) acc += __shfl_down(acc, off);
    if (l == 0) out[NN * 128 + c] = acc * (1.0f / 768.0f);
}

extern "C" void kernel_launch(void* const* d_in, const int* in_sizes, int n_in,
                              void* d_out, int out_size, void* d_ws, size_t ws_size,
                              hipStream_t stream) {
    const float* nf  = (const float*)d_in[0];
    const float* ef  = (const float*)d_in[1];
    const float* adj = (const float*)d_in[2];
    const float* Wn  = (const float*)d_in[3];
    const float* bn  = (const float*)d_in[4];
    const float* We  = (const float*)d_in[5];
    const float* be  = (const float*)d_in[6];
    const float* Wa  = (const float*)d_in[7];
    const float* ba  = (const float*)d_in[8];
    const float* Wu  = (const float*)d_in[9];
    const float* bu  = (const float*)d_in[10];
    float* out = (float*)d_out;

    // workspace carve-up (floats): h | agg | spF | adjT | WeT(bf16) | Wa2T(bf16)
    float* h_buf = (float*)d_ws;
    float* agg   = h_buf + NN * 128;
    float* spF   = agg + NN * 128;
    float* adjT  = spF + NN * 128;
    unsigned short* WeT  = (unsigned short*)(adjT + NN * NN);
    unsigned short* Wa2T = WeT + 128 * 32;

    k_prep<<<1040, 256, 0, stream>>>(adj, adjT, We, Wa, WeT, Wa2T, nf, Wn, bn, ba, h_buf, spF);

    k_big<<<NN, 256, 0, stream>>>(ef, adjT, spF, WeT, Wa2T, be, agg);
    k_upd<0><<<NN / 2, 256, 0, stream>>>(h_buf, agg, Wu, bu, Wa, ba, h_buf, spF, out);
    k_big<<<NN, 256, 0, stream>>>(ef, adjT, spF, WeT, Wa2T, be, agg);
    k_upd<1><<<NN / 2, 256, 0, stream>>>(h_buf, agg, Wu, bu, Wa, ba, h_buf, spF, out);

    k_gemb<<<128, 64, 0, stream>>>(out, out);
}